// Round 1
// baseline (3473.259 us; speedup 1.0000x reference)
//
#include <hip/hip_runtime.h>

#define DIV_UP(a,b) (((a)+(b)-1)/(b))

// ---------------- degree / dinv ----------------
__global__ void deg_init_k(float* deg, int n) {
    int i = blockIdx.x * blockDim.x + threadIdx.x;
    if (i < n) deg[i] = 1.0f;  // self-loop contributes 1
}

__global__ void deg_accum_k(const int* __restrict__ col, float* __restrict__ deg, int E) {
    int stride = gridDim.x * blockDim.x;
    for (int e = blockIdx.x * blockDim.x + threadIdx.x; e < E; e += stride)
        atomicAdd(&deg[col[e]], 1.0f);
}

__global__ void dinv_k(float* deg, int n) {
    int i = blockIdx.x * blockDim.x + threadIdx.x;
    if (i < n) { float d = deg[i]; deg[i] = d > 0.f ? rsqrtf(d) : 0.f; }
}

// ---------------- dense skinny matmul: y[n,OUT] = x[n,IN] @ W (+b, relu) ----------------
template<int IN, int OUT, bool RELU, bool BIAS>
__global__ void matmul_k(const float* __restrict__ x, const float* __restrict__ W,
                         const float* __restrict__ b, float* __restrict__ y, int n) {
    __shared__ float Ws[IN * OUT];
    __shared__ float bs[OUT];
    for (int i = threadIdx.x; i < IN * OUT; i += blockDim.x) Ws[i] = W[i];
    if (BIAS) for (int i = threadIdx.x; i < OUT; i += blockDim.x) bs[i] = b[i];
    __syncthreads();
    int node = blockIdx.x * blockDim.x + threadIdx.x;
    if (node >= n) return;
    float acc[OUT];
#pragma unroll
    for (int j = 0; j < OUT; j++) acc[j] = 0.f;
    const float4* xr = reinterpret_cast<const float4*>(x + (size_t)node * IN);
#pragma unroll
    for (int k4 = 0; k4 < IN / 4; k4++) {
        float4 v = xr[k4];
#pragma unroll
        for (int j = 0; j < OUT; j++) {
            acc[j] += v.x * Ws[(k4*4+0)*OUT + j] + v.y * Ws[(k4*4+1)*OUT + j]
                    + v.z * Ws[(k4*4+2)*OUT + j] + v.w * Ws[(k4*4+3)*OUT + j];
        }
    }
    float* yr = y + (size_t)node * OUT;
#pragma unroll
    for (int j = 0; j < OUT; j++) {
        float v = acc[j] + (BIAS ? bs[j] : 0.f);
        if (RELU) v = fmaxf(v, 0.f);
        yr[j] = v;
    }
}

// ---------------- propagation: agg = D^-1/2 A_hat D^-1/2 h ----------------
// init with self-loop term: agg[i] = h[i] * dinv[i]^2
template<int D>
__global__ void selfloop_init_k(const float* __restrict__ h, const float* __restrict__ dinv,
                                float* __restrict__ agg, int n) {
    constexpr int C = D / 4;
    int idx = blockIdx.x * blockDim.x + threadIdx.x;
    if (idx >= n * C) return;
    int i = idx / C;
    float w = dinv[i]; w *= w;
    float4 v = reinterpret_cast<const float4*>(h)[idx];
    float4 o; o.x = v.x*w; o.y = v.y*w; o.z = v.z*w; o.w = v.w*w;
    reinterpret_cast<float4*>(agg)[idx] = o;
}

template<int D>
__global__ void edge_prop_k(const int* __restrict__ row, const int* __restrict__ col,
                            const float* __restrict__ dinv, const float* __restrict__ h,
                            float* __restrict__ agg, int E) {
    constexpr int C = D / 4;
    int total = E * C;
    int stride = gridDim.x * blockDim.x;
    for (int idx = blockIdx.x * blockDim.x + threadIdx.x; idx < total; idx += stride) {
        int e = idx / C, c = idx % C;
        int r = row[e], t = col[e];
        float w = dinv[r] * dinv[t];
        float4 v = reinterpret_cast<const float4*>(h + (size_t)r * D)[c];
        float* ap = agg + (size_t)t * D + c * 4;
        atomicAdd(ap + 0, v.x * w);
        atomicAdd(ap + 1, v.y * w);
        atomicAdd(ap + 2, v.z * w);
        atomicAdd(ap + 3, v.w * w);
    }
}

// ---------------- bias + relu in place ----------------
template<int D>
__global__ void bias_relu_k(float* __restrict__ h, const float* __restrict__ b, int n) {
    int idx = blockIdx.x * blockDim.x + threadIdx.x;
    if (idx >= n * D) return;
    h[idx] = fmaxf(h[idx] + b[idx % D], 0.f);
}

// ---------------- pooling: segment_max over sorted batch, then log_softmax ----------------
__device__ inline unsigned fkey(float x) {
    unsigned u = __float_as_uint(x);
    return (u & 0x80000000u) ? ~u : (u | 0x80000000u);
}
__device__ inline float funkey(unsigned k) {
    unsigned u = (k & 0x80000000u) ? (k & 0x7FFFFFFFu) : ~k;
    return __uint_as_float(u);
}

__global__ void pool_init_k(unsigned* pooled, int total) {
    int i = blockIdx.x * blockDim.x + threadIdx.x;
    if (i < total) pooled[i] = 0u;  // key-space minimum (acts as -inf sentinel)
}

__global__ void pool_max_k(const float* __restrict__ h4, const float* __restrict__ b4,
                           const int* __restrict__ batch, unsigned* __restrict__ pooled,
                           int n, int num_graphs) {
    __shared__ unsigned lds[128 * 4];
    for (int i = threadIdx.x; i < num_graphs * 4; i += blockDim.x) lds[i] = 0u;
    __syncthreads();
    int i = blockIdx.x * blockDim.x + threadIdx.x;
    if (i < n) {
        int g = batch[i];
        float4 v = reinterpret_cast<const float4*>(h4)[i];
        atomicMax(&lds[g*4+0], fkey(v.x + b4[0]));
        atomicMax(&lds[g*4+1], fkey(v.y + b4[1]));
        atomicMax(&lds[g*4+2], fkey(v.z + b4[2]));
        atomicMax(&lds[g*4+3], fkey(v.w + b4[3]));
    }
    __syncthreads();
    for (int i2 = threadIdx.x; i2 < num_graphs * 4; i2 += blockDim.x) {
        unsigned k = lds[i2];
        if (k) atomicMax(&pooled[i2], k);
    }
}

__global__ void logsoftmax_k(const unsigned* __restrict__ pooled, float* __restrict__ out, int G) {
    int g = blockIdx.x * blockDim.x + threadIdx.x;
    if (g >= G) return;
    float v[4];
#pragma unroll
    for (int j = 0; j < 4; j++) v[j] = funkey(pooled[g*4+j]);
    float m = fmaxf(fmaxf(v[0], v[1]), fmaxf(v[2], v[3]));
    float s = 0.f;
#pragma unroll
    for (int j = 0; j < 4; j++) s += expf(v[j] - m);
    float l = logf(s);
#pragma unroll
    for (int j = 0; j < 4; j++) out[g*4+j] = v[j] - m - l;
}

// ---------------- launch ----------------
extern "C" void kernel_launch(void* const* d_in, const int* in_sizes, int n_in,
                              void* d_out, int out_size, void* d_ws, size_t ws_size,
                              hipStream_t stream) {
    const float* x     = (const float*)d_in[0];
    const int*   ei    = (const int*)d_in[1];
    const int*   batch = (const int*)d_in[2];
    const float* W1 = (const float*)d_in[3];
    const float* b1 = (const float*)d_in[4];
    const float* W2 = (const float*)d_in[5];
    const float* b2 = (const float*)d_in[6];
    const float* W3 = (const float*)d_in[7];
    const float* b3 = (const float*)d_in[8];
    const float* W4 = (const float*)d_in[9];
    const float* b4 = (const float*)d_in[10];

    const int N = in_sizes[2];          // 100000 nodes
    const int E = in_sizes[1] / 2;      // 3.2M edges
    const int G = 128;                  // graphs
    const int* row = ei;
    const int* col = ei + E;

    // workspace layout (floats)
    float* ws   = (float*)d_ws;
    float* dinv = ws;                      // N
    float* bufB = dinv + N;                // N*16
    float* bufA = bufB + (size_t)N * 16;   // N*32
    float* bufC = bufA + (size_t)N * 32;   // N*64
    unsigned* pooled = (unsigned*)(bufC + (size_t)N * 64); // 512

    const int B = 256;
    const int gridN = DIV_UP(N, B);
    const int gridE = 2048;

    // deg -> dinv
    deg_init_k<<<gridN, B, 0, stream>>>(dinv, N);
    deg_accum_k<<<gridE, B, 0, stream>>>(col, dinv, E);
    dinv_k<<<gridN, B, 0, stream>>>(dinv, N);

    // L1: h1 = x@W1 (N x 16) -> bufA ; propagate 16 -> bufB ; bias+relu -> y1 in bufB
    matmul_k<128,16,false,false><<<gridN, B, 0, stream>>>(x, W1, nullptr, bufA, N);
    selfloop_init_k<16><<<DIV_UP(N*4, B), B, 0, stream>>>(bufA, dinv, bufB, N);
    edge_prop_k<16><<<gridE, B, 0, stream>>>(row, col, dinv, bufA, bufB, E);
    bias_relu_k<16><<<DIV_UP(N*16, B), B, 0, stream>>>(bufB, b1, N);

    // L2: propagate y1 (16) -> bufA ; h2 = relu(aggx2@W2+b2) (N x 32) -> bufC
    selfloop_init_k<16><<<DIV_UP(N*4, B), B, 0, stream>>>(bufB, dinv, bufA, N);
    edge_prop_k<16><<<gridE, B, 0, stream>>>(row, col, dinv, bufB, bufA, E);
    matmul_k<16,32,true,true><<<gridN, B, 0, stream>>>(bufA, W2, b2, bufC, N);

    // L3: propagate h2 (32) -> bufA ; h3 = relu(aggx3@W3+b3) (N x 64) -> bufC
    selfloop_init_k<32><<<DIV_UP(N*8, B), B, 0, stream>>>(bufC, dinv, bufA, N);
    edge_prop_k<32><<<gridE, B, 0, stream>>>(row, col, dinv, bufC, bufA, E);
    matmul_k<32,64,true,true><<<gridN, B, 0, stream>>>(bufA, W3, b3, bufC, N);

    // L4: h4 = h3@W4 (N x 4) -> bufA ; propagate 4 -> bufB
    matmul_k<64,4,false,false><<<gridN, B, 0, stream>>>(bufC, W4, nullptr, bufA, N);
    selfloop_init_k<4><<<DIV_UP(N, B), B, 0, stream>>>(bufA, dinv, bufB, N);
    edge_prop_k<4><<<gridE, B, 0, stream>>>(row, col, dinv, bufA, bufB, E);

    // pool (adds b4) + log_softmax
    pool_init_k<<<DIV_UP(G*4, B), B, 0, stream>>>(pooled, G*4);
    pool_max_k<<<gridN, B, 0, stream>>>(bufB, b4, batch, pooled, N, G);
    logsoftmax_k<<<1, 128, 0, stream>>>(pooled, (float*)d_out, G);
}

// Round 2
// 741.937 us; speedup vs baseline: 4.6813x; 4.6813x over previous
//
#include <hip/hip_runtime.h>

#define DIV_UP(a,b) (((a)+(b)-1)/(b))

constexpr int CHUNK = 1024;   // elements per scan block

// ---------------- CSR build ----------------
__global__ void zero_int_k(int* p, int n) {
    int i = blockIdx.x * blockDim.x + threadIdx.x;
    if (i < n) p[i] = 0;
}

__global__ void hist_k(const int* __restrict__ col, int* __restrict__ deg, int E) {
    int stride = gridDim.x * blockDim.x;
    for (int e = blockIdx.x * blockDim.x + threadIdx.x; e < E; e += stride)
        atomicAdd(&deg[col[e]], 1);
}

__global__ void dinv_k(const int* __restrict__ deg, float* __restrict__ dinv, int n) {
    int i = blockIdx.x * blockDim.x + threadIdx.x;
    if (i < n) dinv[i] = rsqrtf(1.0f + (float)deg[i]);   // +1 self-loop
}

__global__ void chunk_sum_k(const int* __restrict__ deg, int* __restrict__ csum, int n) {
    __shared__ int lds[256];
    int base = blockIdx.x * CHUNK;
    int s = 0;
    for (int i = threadIdx.x; i < CHUNK; i += 256) {
        int idx = base + i;
        s += (idx < n) ? deg[idx] : 0;
    }
    lds[threadIdx.x] = s; __syncthreads();
    for (int off = 128; off > 0; off >>= 1) {
        if (threadIdx.x < off) lds[threadIdx.x] += lds[threadIdx.x + off];
        __syncthreads();
    }
    if (threadIdx.x == 0) csum[blockIdx.x] = lds[0];
}

// exclusive scan of chunk sums in place (nb <= 256)
__global__ void chunk_scan_k(int* csum, int nb) {
    __shared__ int lds[256];
    int v = (threadIdx.x < nb) ? csum[threadIdx.x] : 0;
    lds[threadIdx.x] = v; __syncthreads();
    for (int off = 1; off < 256; off <<= 1) {
        int t = (threadIdx.x >= off) ? lds[threadIdx.x - off] : 0;
        __syncthreads();
        lds[threadIdx.x] += t;
        __syncthreads();
    }
    if (threadIdx.x < nb) csum[threadIdx.x] = lds[threadIdx.x] - v;
}

// write exclusive offsets into cur (scatter will shift them to inclusive)
__global__ void offsets_k(const int* __restrict__ deg, const int* __restrict__ csum,
                          int* __restrict__ cur, int n) {
    __shared__ int lds[256];
    int base = blockIdx.x * CHUNK + threadIdx.x * 4;
    int d[4]; int s = 0;
#pragma unroll
    for (int j = 0; j < 4; j++) { int idx = base + j; d[j] = (idx < n) ? deg[idx] : 0; s += d[j]; }
    lds[threadIdx.x] = s; __syncthreads();
    for (int off = 1; off < 256; off <<= 1) {
        int t = (threadIdx.x >= off) ? lds[threadIdx.x - off] : 0;
        __syncthreads();
        lds[threadIdx.x] += t;
        __syncthreads();
    }
    int excl = lds[threadIdx.x] - s + csum[blockIdx.x];
#pragma unroll
    for (int j = 0; j < 4; j++) {
        int idx = base + j;
        if (idx < n) cur[idx] = excl;
        excl += d[j];
    }
}

// scatter edge sources into CSR; cur[i] ends at off[i+1]
__global__ void csr_scatter_k(const int* __restrict__ row, const int* __restrict__ col,
                              int* __restrict__ cur, int* __restrict__ csr_src, int E) {
    int stride = gridDim.x * blockDim.x;
    for (int e = blockIdx.x * blockDim.x + threadIdx.x; e < E; e += stride) {
        int t = col[e];
        int p = atomicAdd(&cur[t], 1);
        csr_src[p] = row[e];
    }
}

// ---------------- gather propagation: agg = D^-1/2 A_hat D^-1/2 h ----------------
// cur[] holds inclusive end offsets after scatter: seg(i) = [i? cur[i-1]:0, cur[i])
template<int D, bool RELU, bool BIAS>
__global__ void gather_prop_k(const float* __restrict__ h, const float* __restrict__ dinv,
                              const int* __restrict__ cur, const int* __restrict__ csr_src,
                              const float* __restrict__ b, float* __restrict__ out, int n) {
    constexpr int TPN = D / 4;
    int tid = blockIdx.x * blockDim.x + threadIdx.x;
    int node = tid / TPN, t = tid % TPN;
    if (node >= n) return;
    float di = dinv[node];
    float4 acc = reinterpret_cast<const float4*>(h + (size_t)node * D)[t];
    acc.x *= di; acc.y *= di; acc.z *= di; acc.w *= di;   // self-loop: * di again at end
    int e0 = node ? cur[node - 1] : 0;
    int e1 = cur[node];
    for (int e = e0; e < e1; e++) {
        int s = csr_src[e];
        float w = dinv[s];
        float4 v = reinterpret_cast<const float4*>(h + (size_t)s * D)[t];
        acc.x += v.x * w; acc.y += v.y * w; acc.z += v.z * w; acc.w += v.w * w;
    }
    acc.x *= di; acc.y *= di; acc.z *= di; acc.w *= di;
    if (BIAS) {
        acc.x += b[t*4+0]; acc.y += b[t*4+1]; acc.z += b[t*4+2]; acc.w += b[t*4+3];
    }
    if (RELU) {
        acc.x = fmaxf(acc.x, 0.f); acc.y = fmaxf(acc.y, 0.f);
        acc.z = fmaxf(acc.z, 0.f); acc.w = fmaxf(acc.w, 0.f);
    }
    reinterpret_cast<float4*>(out + (size_t)node * D)[t] = acc;
}

// ---------------- dense skinny matmul: y[n,OUT] = x[n,IN] @ W (+b, relu) ----------------
template<int IN, int OUT, bool RELU, bool BIAS>
__global__ void matmul_k(const float* __restrict__ x, const float* __restrict__ W,
                         const float* __restrict__ b, float* __restrict__ y, int n) {
    __shared__ float Ws[IN * OUT];
    __shared__ float bs[OUT];
    for (int i = threadIdx.x; i < IN * OUT; i += blockDim.x) Ws[i] = W[i];
    if (BIAS) for (int i = threadIdx.x; i < OUT; i += blockDim.x) bs[i] = b[i];
    __syncthreads();
    int node = blockIdx.x * blockDim.x + threadIdx.x;
    if (node >= n) return;
    float acc[OUT];
#pragma unroll
    for (int j = 0; j < OUT; j++) acc[j] = 0.f;
    const float4* xr = reinterpret_cast<const float4*>(x + (size_t)node * IN);
#pragma unroll
    for (int k4 = 0; k4 < IN / 4; k4++) {
        float4 v = xr[k4];
#pragma unroll
        for (int j = 0; j < OUT; j++) {
            acc[j] += v.x * Ws[(k4*4+0)*OUT + j] + v.y * Ws[(k4*4+1)*OUT + j]
                    + v.z * Ws[(k4*4+2)*OUT + j] + v.w * Ws[(k4*4+3)*OUT + j];
        }
    }
    float* yr = y + (size_t)node * OUT;
#pragma unroll
    for (int j = 0; j < OUT; j++) {
        float v = acc[j] + (BIAS ? bs[j] : 0.f);
        if (RELU) v = fmaxf(v, 0.f);
        yr[j] = v;
    }
}

// ---------------- pooling + log_softmax ----------------
__device__ inline unsigned fkey(float x) {
    unsigned u = __float_as_uint(x);
    return (u & 0x80000000u) ? ~u : (u | 0x80000000u);
}
__device__ inline float funkey(unsigned k) {
    unsigned u = (k & 0x80000000u) ? (k & 0x7FFFFFFFu) : ~k;
    return __uint_as_float(u);
}

__global__ void pool_init_k(unsigned* pooled, int total) {
    int i = blockIdx.x * blockDim.x + threadIdx.x;
    if (i < total) pooled[i] = 0u;
}

__global__ void pool_max_k(const float* __restrict__ h4, const float* __restrict__ b4,
                           const int* __restrict__ batch, unsigned* __restrict__ pooled,
                           int n, int num_graphs) {
    __shared__ unsigned lds[128 * 4];
    for (int i = threadIdx.x; i < num_graphs * 4; i += blockDim.x) lds[i] = 0u;
    __syncthreads();
    int i = blockIdx.x * blockDim.x + threadIdx.x;
    if (i < n) {
        int g = batch[i];
        float4 v = reinterpret_cast<const float4*>(h4)[i];
        atomicMax(&lds[g*4+0], fkey(v.x + b4[0]));
        atomicMax(&lds[g*4+1], fkey(v.y + b4[1]));
        atomicMax(&lds[g*4+2], fkey(v.z + b4[2]));
        atomicMax(&lds[g*4+3], fkey(v.w + b4[3]));
    }
    __syncthreads();
    for (int i2 = threadIdx.x; i2 < num_graphs * 4; i2 += blockDim.x) {
        unsigned k = lds[i2];
        if (k) atomicMax(&pooled[i2], k);
    }
}

__global__ void logsoftmax_k(const unsigned* __restrict__ pooled, float* __restrict__ out, int G) {
    int g = blockIdx.x * blockDim.x + threadIdx.x;
    if (g >= G) return;
    float v[4];
#pragma unroll
    for (int j = 0; j < 4; j++) v[j] = funkey(pooled[g*4+j]);
    float m = fmaxf(fmaxf(v[0], v[1]), fmaxf(v[2], v[3]));
    float s = 0.f;
#pragma unroll
    for (int j = 0; j < 4; j++) s += expf(v[j] - m);
    float l = logf(s);
#pragma unroll
    for (int j = 0; j < 4; j++) out[g*4+j] = v[j] - m - l;
}

// ---------------- launch ----------------
extern "C" void kernel_launch(void* const* d_in, const int* in_sizes, int n_in,
                              void* d_out, int out_size, void* d_ws, size_t ws_size,
                              hipStream_t stream) {
    const float* x     = (const float*)d_in[0];
    const int*   ei    = (const int*)d_in[1];
    const int*   batch = (const int*)d_in[2];
    const float* W1 = (const float*)d_in[3];
    const float* b1 = (const float*)d_in[4];
    const float* W2 = (const float*)d_in[5];
    const float* b2 = (const float*)d_in[6];
    const float* W3 = (const float*)d_in[7];
    const float* b3 = (const float*)d_in[8];
    const float* W4 = (const float*)d_in[9];
    const float* b4 = (const float*)d_in[10];

    const int N = in_sizes[2];          // 100000
    const int E = in_sizes[1] / 2;      // 3.2M
    const int G = 128;
    const int* row = ei;
    const int* col = ei + E;

    // workspace layout
    float* ws    = (float*)d_ws;
    float* dinv  = ws;                              // N floats
    int*   deg   = (int*)(dinv + N);                // N ints
    int*   cur   = deg + N;                         // N ints (excl offsets -> incl ends)
    int*   csum  = cur + N;                         // 256 ints
    int*   csr   = csum + 256;                      // E ints
    float* f16a  = (float*)(csr + E);               // N*16
    float* f16b  = f16a + (size_t)N * 16;           // N*16
    float* f32a  = f16b + (size_t)N * 16;           // N*32
    float* f32b  = f32a + (size_t)N * 32;           // N*32
    float* f64   = f16a;                            // alias: N*64 == 16+16+32
    float* f4a   = f32b;                            // alias (f32b dead by then)
    float* f4b   = f32b + (size_t)N * 4;
    unsigned* pooled = (unsigned*)(f32b + (size_t)N * 32);

    const int B = 256;
    const int gridN = DIV_UP(N, B);
    const int gridE = 2048;
    const int nb = DIV_UP(N, CHUNK);   // 98 scan chunks

    // CSR build + dinv
    zero_int_k<<<gridN, B, 0, stream>>>(deg, N);
    hist_k<<<gridE, B, 0, stream>>>(col, deg, E);
    dinv_k<<<gridN, B, 0, stream>>>(deg, dinv, N);
    chunk_sum_k<<<nb, 256, 0, stream>>>(deg, csum, N);
    chunk_scan_k<<<1, 256, 0, stream>>>(csum, nb);
    offsets_k<<<nb, 256, 0, stream>>>(deg, csum, cur, N);
    csr_scatter_k<<<gridE, B, 0, stream>>>(row, col, cur, csr, E);

    // L1: h1 = x@W1 -> f16a ; gather+bias+relu -> f16b
    matmul_k<128,16,false,false><<<gridN, B, 0, stream>>>(x, W1, nullptr, f16a, N);
    gather_prop_k<16,true,true><<<DIV_UP(N*4, B), B, 0, stream>>>(f16a, dinv, cur, csr, b1, f16b, N);

    // L2: gather f16b -> f16a ; matmul 16->32 (+b2, relu) -> f32a
    gather_prop_k<16,false,false><<<DIV_UP(N*4, B), B, 0, stream>>>(f16b, dinv, cur, csr, nullptr, f16a, N);
    matmul_k<16,32,true,true><<<gridN, B, 0, stream>>>(f16a, W2, b2, f32a, N);

    // L3: gather f32a -> f32b ; matmul 32->64 (+b3, relu) -> f64 (aliases f16a/b,f32a)
    gather_prop_k<32,false,false><<<DIV_UP(N*8, B), B, 0, stream>>>(f32a, dinv, cur, csr, nullptr, f32b, N);
    matmul_k<32,64,true,true><<<gridN, B, 0, stream>>>(f32b, W3, b3, f64, N);

    // L4: matmul 64->4 -> f4a (aliases f32b) ; gather -> f4b
    matmul_k<64,4,false,false><<<gridN, B, 0, stream>>>(f64, W4, nullptr, f4a, N);
    gather_prop_k<4,false,false><<<DIV_UP(N, B), B, 0, stream>>>(f4a, dinv, cur, csr, nullptr, f4b, N);

    // pool (adds b4) + log_softmax
    pool_init_k<<<DIV_UP(G*4, B), B, 0, stream>>>(pooled, G*4);
    pool_max_k<<<gridN, B, 0, stream>>>(f4b, b4, batch, pooled, N, G);
    logsoftmax_k<<<1, 128, 0, stream>>>(pooled, (float*)d_out, G);
}